// Round 5
// baseline (206.517 us; speedup 1.0000x reference)
//
#include <hip/hip_runtime.h>
#include <math.h>

#define BS   8192
#define DD   768
#define NC   64
#define NCL  500
#define CS   100
#define NY   1000
#define EPSN 1e-12f

// Role order: tmat first (long pole starts earliest), then cmean, gram, U.
#define NB_TMAT  128
#define NB_CMEAN 375
#define NB_GRAM  64
#define NB_U     16
#define NB_A     (NB_TMAT + NB_CMEAN + NB_GRAM + NB_U)

// ============ PHASE A: tmat || cmean || gram || U = C^T W ============
__global__ __launch_bounds__(256) void k_phaseA(
    const float* __restrict__ clusters, const float* __restrict__ C,
    const float* __restrict__ W, const float* __restrict__ X,
    float* __restrict__ cm, float* __restrict__ gram,
    float* __restrict__ U, float* __restrict__ T) {
    __shared__ __align__(16) char smem_raw[34816];
    int b   = blockIdx.x;
    int tid = threadIdx.x;

    if (b < NB_TMAT) {
        // ---- T = X @ C [8192,64]: 64x64 tile, K-chunk 32, transposed X in LDS.
        // R4 post-mortem: old tmat did ~6 scalar ds_read per 8 FMA -> LDS-bound,
        // ~97us long pole. New: 2 x ds_read_b128 per 16 FMA; X-read is a
        // 16-lane broadcast (near-free), C-read is 2-way (free, m136).
        float (*Xt)[68] = (float(*)[68])smem_raw;                  // [32][68] Xt[k][row]
        float (*Cs)[68] = (float(*)[68])(smem_raw + 32 * 68 * 4);  // [32][68] Cs[k][col]
        int r0g = b * 64;
        int tx  = tid & 15;          // cols tx*4..+3
        int ty  = tid >> 4;          // rows ty*4..+3
        float acc[4][4] = {};
        for (int kc = 0; kc < DD; kc += 32) {
            __syncthreads();
            {   // stage X transposed: 64 rows x 32 k; 2 float4 per thread
                int row = tid & 63;
                int kq  = (tid >> 6) * 2;        // 0,2,4,6
                #pragma unroll
                for (int u = 0; u < 2; ++u) {
                    float4 v = *((const float4*)(X + (size_t)(r0g + row) * DD + kc + (kq + u) * 4));
                    Xt[(kq + u) * 4 + 0][row] = v.x;
                    Xt[(kq + u) * 4 + 1][row] = v.y;
                    Xt[(kq + u) * 4 + 2][row] = v.z;
                    Xt[(kq + u) * 4 + 3][row] = v.w;
                }
            }
            {   // stage C: 32 k x 64 cols; 2 float4 per thread, coalesced
                int c4 = tid & 15;
                int k0 = tid >> 4;               // 0..15
                #pragma unroll
                for (int u = 0; u < 2; ++u) {
                    int kk = k0 + u * 16;
                    *((float4*)&Cs[kk][c4 * 4]) =
                        *((const float4*)(C + (size_t)(kc + kk) * 64 + c4 * 4));
                }
            }
            __syncthreads();
            #pragma unroll 8
            for (int k = 0; k < 32; ++k) {
                float4 xa = *((float4*)&Xt[k][ty * 4]);
                float4 cb = *((float4*)&Cs[k][tx * 4]);
                float xv[4] = {xa.x, xa.y, xa.z, xa.w};
                float cv[4] = {cb.x, cb.y, cb.z, cb.w};
                #pragma unroll
                for (int r = 0; r < 4; ++r)
                    #pragma unroll
                    for (int c = 0; c < 4; ++c)
                        acc[r][c] = fmaf(xv[r], cv[c], acc[r][c]);
            }
        }
        #pragma unroll
        for (int r = 0; r < 4; ++r) {
            float4 o = {acc[r][0], acc[r][1], acc[r][2], acc[r][3]};
            *((float4*)(T + (size_t)(r0g + ty * 4 + r) * 64 + tx * 4)) = o;
        }
    } else if (b < NB_TMAT + NB_CMEAN) {
        // ---- cluster_mean: [500,100,768] -> [500,768], float4 streaming ----
        int idx = (b - NB_TMAT) * 256 + tid;     // 375*256 == 500*768/4 exactly
        int r  = idx / (DD / 4);
        int d4 = idx % (DD / 4);
        const float4* base = (const float4*)(clusters + (size_t)r * CS * DD) + d4;
        float4 acc = {0.f, 0.f, 0.f, 0.f};
        for (int s = 0; s < CS; ++s) {
            float4 v = base[(size_t)s * (DD / 4)];
            acc.x += v.x; acc.y += v.y; acc.z += v.z; acc.w += v.w;
        }
        const float sc = 1.0f / CS;
        acc.x *= sc; acc.y *= sc; acc.z *= sc; acc.w *= sc;
        ((float4*)cm)[idx] = acc;
    } else if (b < NB_TMAT + NB_CMEAN + NB_GRAM) {
        // ---- gram = C^T C [64,64] ----
        int j   = b - (NB_TMAT + NB_CMEAN);
        int i   = tid & 63;
        int seg = tid >> 6;
        float p = 0.f;
        for (int k = seg * 192; k < seg * 192 + 192; ++k)
            p += C[k * NC + i] * C[k * NC + j];
        float (*red)[64] = (float(*)[64])smem_raw;
        red[seg][i] = p;
        __syncthreads();
        if (seg == 0)
            gram[i * NC + j] = red[0][i] + red[1][i] + red[2][i] + red[3][i];
    } else {
        // ---- U = C^T W [64,1000], 64x64 tile, K-chunk 64 ----
        int nt = b - (NB_TMAT + NB_CMEAN + NB_GRAM);
        int n0 = nt * 64;
        float (*Csh)[68] = (float(*)[68])smem_raw;                 // [k][i]
        float (*Wsh)[68] = (float(*)[68])(smem_raw + 64 * 68 * 4); // [k][n]
        int iq = tid & 15;
        int nq = tid >> 4;
        float acc[4][4] = {};
        for (int kc = 0; kc < DD; kc += 64) {
            __syncthreads();
            {   // stage C chunk
                int i4 = tid & 15, kk = tid >> 4;
                #pragma unroll
                for (int pass = 0; pass < 4; ++pass) {
                    int k = kk + pass * 16;
                    *((float4*)&Csh[k][i4 * 4]) =
                        *((const float4*)(C + (size_t)(kc + k) * 64 + i4 * 4));
                }
            }
            {   // stage W chunk (zero-pad n >= 1000)
                int n4 = tid & 15, kk = tid >> 4;
                #pragma unroll
                for (int pass = 0; pass < 4; ++pass) {
                    int k = kk + pass * 16;
                    int n = n0 + n4 * 4;
                    float4 v = {0.f, 0.f, 0.f, 0.f};
                    if (n < NY)
                        v = *((const float4*)(W + (size_t)(kc + k) * NY + n));
                    *((float4*)&Wsh[k][n4 * 4]) = v;
                }
            }
            __syncthreads();
            #pragma unroll 4
            for (int k = 0; k < 64; ++k) {
                float4 a = *((float4*)&Csh[k][iq * 4]);
                float4 w = *((float4*)&Wsh[k][nq * 4]);
                float av[4] = {a.x, a.y, a.z, a.w};
                float wv[4] = {w.x, w.y, w.z, w.w};
                #pragma unroll
                for (int ii = 0; ii < 4; ++ii)
                    #pragma unroll
                    for (int nn = 0; nn < 4; ++nn)
                        acc[ii][nn] += av[ii] * wv[nn];
            }
        }
        int n = n0 + nq * 4;
        if (n < NY) {
            #pragma unroll
            for (int ii = 0; ii < 4; ++ii) {
                int i = iq * 4 + ii;
                float4 o = {acc[ii][0], acc[ii][1], acc[ii][2], acc[ii][3]};
                *((float4*)(U + (size_t)i * NY + n)) = o;
            }
        }
    }
}

// ============ PHASE B: inv (block 0) || score (blocks 1..500) ============
__global__ __launch_bounds__(256) void k_phaseB(
    const float* __restrict__ gram, const float* __restrict__ cm,
    const float* __restrict__ C, float* __restrict__ ginv,
    float* __restrict__ S) {
    int b   = blockIdx.x;
    int tid = threadIdx.x;
    if (b == 0) {
        // register-resident Gauss-Jordan (R3 body, verified)
        int c = tid & 63;
        int q = tid >> 6;
        float a[16], bb[16];
        #pragma unroll
        for (int i = 0; i < 16; ++i) {
            int r = q * 16 + i;
            a[i]  = gram[r * 64 + c];
            bb[i] = (r == c) ? 1.f : 0.f;
        }
        __shared__ float asr[2][64];
        __shared__ float bsr[2][64];
        for (int p = 0; p < 64; ++p) {
            int qp  = p >> 4;
            int lp  = p & 15;
            int par = p & 1;
            if (q == qp) {
                float ap = 0.f, bp = 0.f;
                #pragma unroll
                for (int i = 0; i < 16; ++i)
                    if (i == lp) { ap = a[i]; bp = bb[i]; }
                float App = __shfl(ap, p);
                float s   = 1.0f / App;
                asr[par][c] = ap * s;
                bsr[par][c] = bp * s;
            }
            __syncthreads();
            float as_ = asr[par][c];
            float bs_ = bsr[par][c];
            #pragma unroll
            for (int i = 0; i < 16; ++i) {
                float f = __shfl(a[i], p);
                bool isp = (q == qp) && (i == lp);
                a[i]  = isp ? as_ : fmaf(-f, as_, a[i]);
                bb[i] = isp ? bs_ : fmaf(-f, bs_, bb[i]);
            }
        }
        #pragma unroll
        for (int i = 0; i < 16; ++i)
            ginv[(q * 16 + i) * 64 + c] = bb[i];
    } else {
        // score: S = |cm @ C| / colnorm(C)
        int r   = b - 1;
        int c   = tid & 63;
        int seg = tid >> 6;
        const float* cmr = cm + (size_t)r * DD;
        float p = 0.f;
        for (int k = seg * 192; k < seg * 192 + 192; ++k)
            p += cmr[k] * C[k * 64 + c];
        __shared__ float red[4][64];
        red[seg][c] = p;
        __syncthreads();
        if (seg == 0) {
            float s   = fabsf(red[0][c] + red[1][c] + red[2][c] + red[3][c]);
            float nrm = fmaxf(sqrtf(gram[c * 64 + c]), EPSN);
            S[r * 64 + c] = s / nrm;
        }
    }
}

// ============ PHASE C: V = Ginv @ U (blocks 0..63) || sparse (block 64) ============
__global__ __launch_bounds__(256) void k_phaseC(
    const float* __restrict__ ginv, const float* __restrict__ U,
    const float* __restrict__ S, float* __restrict__ V,
    float* __restrict__ out2) {
    int b   = blockIdx.x;
    int tid = threadIdx.x;
    if (b < 64) {
        int i = b;
        float acc[4] = {0.f, 0.f, 0.f, 0.f};
        for (int j = 0; j < 64; ++j) {
            float g = ginv[i * 64 + j];          // block-uniform -> s_load
            #pragma unroll
            for (int q = 0; q < 4; ++q) {
                int n = tid + q * 256;
                if (n < NY) acc[q] = fmaf(g, U[(size_t)j * NY + n], acc[q]);
            }
        }
        #pragma unroll
        for (int q = 0; q < 4; ++q) {
            int n = tid + q * 256;
            if (n < NY) V[(size_t)i * NY + n] = acc[q];
        }
    } else {
        // sparse losses from S
        __shared__ float colred[4][64];
        __shared__ float rn[64];
        __shared__ float trc[64];
        __shared__ float r1[4], r2[4];
        int c = tid & 63, seg = tid >> 6;
        float p = 0.f;
        for (int r = seg; r < NCL; r += 4) {
            float v = S[r * 64 + c];
            p += v * v;
        }
        colred[seg][c] = p;
        __syncthreads();
        if (seg == 0) {
            float n2  = colred[0][c] + colred[1][c] + colred[2][c] + colred[3][c];
            float inv = 1.0f / fmaxf(sqrtf(n2), EPSN);
            rn[c]  = inv;
            trc[c] = n2 * inv * inv;
        }
        __syncthreads();
        float l1p = 0.f, l2p = 0.f;
        for (int r = tid; r < NCL; r += 256) {
            float rs = 0.f;
            #pragma unroll
            for (int cc = 0; cc < 64; ++cc)
                rs += S[r * 64 + cc] * rn[cc];
            l1p += rs;
            l2p += rs * rs;
        }
        #pragma unroll
        for (int off = 32; off > 0; off >>= 1) {
            l1p += __shfl_down(l1p, off);
            l2p += __shfl_down(l2p, off);
        }
        int wave = tid >> 6, lane = tid & 63;
        if (lane == 0) { r1[wave] = l1p; r2[wave] = l2p; }
        __syncthreads();
        if (tid == 0) {
            float L1 = r1[0] + r1[1] + r1[2] + r1[3];
            float L2 = r2[0] + r2[1] + r2[2] + r2[3];
            float tr = 0.f;
            #pragma unroll
            for (int cc = 0; cc < 64; ++cc) tr += trc[cc];
            out2[0] = L1;
            out2[1] = L2 - tr;
        }
    }
}

// ============ PHASE D: y = T @ V + b [8192,1000], tile 64x128 ============
__global__ __launch_bounds__(256) void k_ypred(const float* __restrict__ T,
                                               const float* __restrict__ V,
                                               const float* __restrict__ bh,
                                               float* __restrict__ Y) {
    __shared__ float Ts[64][68];    // transposed: Ts[k][row]
    __shared__ float Vs[64][128];
    int tid = threadIdx.x;
    int r0g = blockIdx.x * 64;
    int c0g = blockIdx.y * 128;
    {   // stage T transposed
        int kf = tid & 15;
        int rr = tid >> 4;
        #pragma unroll
        for (int pass = 0; pass < 4; ++pass) {
            int row = rr + pass * 16;
            float4 a = *((const float4*)(T + (size_t)(r0g + row) * 64 + kf * 4));
            Ts[kf * 4 + 0][row] = a.x;
            Ts[kf * 4 + 1][row] = a.y;
            Ts[kf * 4 + 2][row] = a.z;
            Ts[kf * 4 + 3][row] = a.w;
        }
    }
    {   // stage V (zero-pad cols >= 1000)
        int cf = tid & 31;
        int kk = tid >> 5;
        #pragma unroll
        for (int pass = 0; pass < 8; ++pass) {
            int k = kk + pass * 8;
            int c = c0g + cf * 4;
            float4 v = {0.f, 0.f, 0.f, 0.f};
            if (c < NY) v = *((const float4*)(V + (size_t)k * NY + c));
            *((float4*)&Vs[k][cf * 4]) = v;
        }
    }
    __syncthreads();
    int cx = tid & 15;
    int ry = tid >> 4;
    float acc[4][8] = {};
    #pragma unroll 2
    for (int k = 0; k < 64; ++k) {
        float4 a  = *((float4*)&Ts[k][ry * 4]);
        float4 b0 = *((float4*)&Vs[k][cx * 8]);
        float4 b1 = *((float4*)&Vs[k][cx * 8 + 4]);
        float av[4] = {a.x, a.y, a.z, a.w};
        float bv[8] = {b0.x, b0.y, b0.z, b0.w, b1.x, b1.y, b1.z, b1.w};
        #pragma unroll
        for (int r = 0; r < 4; ++r)
            #pragma unroll
            for (int c = 0; c < 8; ++c)
                acc[r][c] += av[r] * bv[c];
    }
    #pragma unroll
    for (int r = 0; r < 4; ++r) {
        int row   = r0g + ry * 4 + r;
        int cbase = c0g + cx * 8;
        #pragma unroll
        for (int cq = 0; cq < 2; ++cq) {
            int c = cbase + cq * 4;
            if (c < NY) {
                float4 o;
                o.x = acc[r][cq * 4 + 0] + bh[c + 0];
                o.y = acc[r][cq * 4 + 1] + bh[c + 1];
                o.z = acc[r][cq * 4 + 2] + bh[c + 2];
                o.w = acc[r][cq * 4 + 3] + bh[c + 3];
                *((float4*)(Y + (size_t)row * NY + c)) = o;
            }
        }
    }
}

extern "C" void kernel_launch(void* const* d_in, const int* in_sizes, int n_in,
                              void* d_out, int out_size, void* d_ws, size_t ws_size,
                              hipStream_t stream) {
    const float* X        = (const float*)d_in[0];   // [8192,768]
    const float* clusters = (const float*)d_in[1];   // [500,100,768]
    const float* C        = (const float*)d_in[2];   // [768,64]
    const float* W        = (const float*)d_in[3];   // [768,1000]
    const float* bh       = (const float*)d_in[4];   // [1000]
    float* out = (float*)d_out;                      // y_pred, L1, L2
    float* ws  = (float*)d_ws;

    float* cm   = ws;                 // 500*768   = 384000
    float* gram = cm   + 384000;      // 4096
    float* ginv = gram + 4096;        // 4096
    float* U    = ginv + 4096;        // 64*1000   = 64000
    float* V    = U    + 64000;       // 64*1000   = 64000
    float* T    = V    + 64000;       // 8192*64   = 524288
    float* S    = T    + 524288;      // 500*64    = 32000

    k_phaseA<<<dim3(NB_A),    dim3(256), 0, stream>>>(clusters, C, W, X, cm, gram, U, T);
    k_phaseB<<<dim3(501),     dim3(256), 0, stream>>>(gram, cm, C, ginv, S);
    k_phaseC<<<dim3(65),      dim3(256), 0, stream>>>(ginv, U, S, V, out + (size_t)BS * NY);
    k_ypred <<<dim3(128, 8),  dim3(256), 0, stream>>>(T, V, bh, out);
}

// Round 6
// 175.727 us; speedup vs baseline: 1.1752x; 1.1752x over previous
//
#include <hip/hip_runtime.h>
#include <math.h>

#define BS   8192
#define DD   768
#define NC   64
#define NCL  500
#define CS   100
#define NY   1000
#define EPSN 1e-12f

// phaseA role layout: cmean (stream) first, then tmat, gram, U.
#define NB_CMEAN 375
#define NB_TMAT  128
#define NB_GRAM  64
#define NB_U     16
#define NB_A     (NB_CMEAN + NB_TMAT + NB_GRAM + NB_U)

// ============ PHASE A: cmean || tmat || gram || U = C^T W ============
__global__ __launch_bounds__(256) void k_phaseA(
    const float* __restrict__ clusters, const float* __restrict__ C,
    const float* __restrict__ W, const float* __restrict__ X,
    float* __restrict__ cm, float* __restrict__ gram,
    float* __restrict__ U, float* __restrict__ T) {
    __shared__ __align__(16) char smem_raw[34816];
    int b   = blockIdx.x;
    int tid = threadIdx.x;

    if (b < NB_CMEAN) {
        // ---- cluster_mean. R5 post-mortem: acc-gated loop kept ~1 load in
        // flight -> 100 x L3-latency serial chain. Fix: 4x unroll with 4
        // independent accumulators -> 4+ loads outstanding.
        int idx = b * 256 + tid;                 // 375*256 == 500*192 float4s
        int r  = idx / (DD / 4);
        int d4 = idx % (DD / 4);
        const float4* base = (const float4*)(clusters + (size_t)r * CS * DD) + d4;
        float4 a0 = {0,0,0,0}, a1 = {0,0,0,0}, a2 = {0,0,0,0}, a3 = {0,0,0,0};
        for (int s = 0; s < CS; s += 4) {
            float4 v0 = base[(size_t)(s + 0) * (DD / 4)];
            float4 v1 = base[(size_t)(s + 1) * (DD / 4)];
            float4 v2 = base[(size_t)(s + 2) * (DD / 4)];
            float4 v3 = base[(size_t)(s + 3) * (DD / 4)];
            a0.x += v0.x; a0.y += v0.y; a0.z += v0.z; a0.w += v0.w;
            a1.x += v1.x; a1.y += v1.y; a1.z += v1.z; a1.w += v1.w;
            a2.x += v2.x; a2.y += v2.y; a2.z += v2.z; a2.w += v2.w;
            a3.x += v3.x; a3.y += v3.y; a3.z += v3.z; a3.w += v3.w;
        }
        float4 o;
        const float sc = 1.0f / CS;
        o.x = (a0.x + a1.x + a2.x + a3.x) * sc;
        o.y = (a0.y + a1.y + a2.y + a3.y) * sc;
        o.z = (a0.z + a1.z + a2.z + a3.z) * sc;
        o.w = (a0.w + a1.w + a2.w + a3.w) * sc;
        ((float4*)cm)[idx] = o;
    } else if (b < NB_CMEAN + NB_TMAT) {
        // ---- T = X @ C [8192,64]: 64x64 tile, K-chunk 32 (R5 body) ----
        int blk = b - NB_CMEAN;
        float (*Xt)[68] = (float(*)[68])smem_raw;                  // Xt[k][row]
        float (*Cs)[68] = (float(*)[68])(smem_raw + 32 * 68 * 4);  // Cs[k][col]
        int r0g = blk * 64;
        int tx  = tid & 15;
        int ty  = tid >> 4;
        float acc[4][4] = {};
        for (int kc = 0; kc < DD; kc += 32) {
            __syncthreads();
            {
                int row = tid & 63;
                int kq  = (tid >> 6) * 2;
                #pragma unroll
                for (int u = 0; u < 2; ++u) {
                    float4 v = *((const float4*)(X + (size_t)(r0g + row) * DD + kc + (kq + u) * 4));
                    Xt[(kq + u) * 4 + 0][row] = v.x;
                    Xt[(kq + u) * 4 + 1][row] = v.y;
                    Xt[(kq + u) * 4 + 2][row] = v.z;
                    Xt[(kq + u) * 4 + 3][row] = v.w;
                }
            }
            {
                int c4 = tid & 15;
                int k0 = tid >> 4;
                #pragma unroll
                for (int u = 0; u < 2; ++u) {
                    int kk = k0 + u * 16;
                    *((float4*)&Cs[kk][c4 * 4]) =
                        *((const float4*)(C + (size_t)(kc + kk) * 64 + c4 * 4));
                }
            }
            __syncthreads();
            #pragma unroll 8
            for (int k = 0; k < 32; ++k) {
                float4 xa = *((float4*)&Xt[k][ty * 4]);
                float4 cb = *((float4*)&Cs[k][tx * 4]);
                float xv[4] = {xa.x, xa.y, xa.z, xa.w};
                float cv[4] = {cb.x, cb.y, cb.z, cb.w};
                #pragma unroll
                for (int r = 0; r < 4; ++r)
                    #pragma unroll
                    for (int c = 0; c < 4; ++c)
                        acc[r][c] = fmaf(xv[r], cv[c], acc[r][c]);
            }
        }
        #pragma unroll
        for (int r = 0; r < 4; ++r) {
            float4 o = {acc[r][0], acc[r][1], acc[r][2], acc[r][3]};
            *((float4*)(T + (size_t)(r0g + ty * 4 + r) * 64 + tx * 4)) = o;
        }
    } else if (b < NB_CMEAN + NB_TMAT + NB_GRAM) {
        // ---- gram = C^T C [64,64] ----
        int j   = b - (NB_CMEAN + NB_TMAT);
        int i   = tid & 63;
        int seg = tid >> 6;
        float p = 0.f;
        for (int k = seg * 192; k < seg * 192 + 192; ++k)
            p += C[k * NC + i] * C[k * NC + j];
        float (*red)[64] = (float(*)[64])smem_raw;
        red[seg][i] = p;
        __syncthreads();
        if (seg == 0)
            gram[i * NC + j] = red[0][i] + red[1][i] + red[2][i] + red[3][i];
    } else {
        // ---- U = C^T W [64,1000], 64x64 tile, K-chunk 64 ----
        int nt = b - (NB_CMEAN + NB_TMAT + NB_GRAM);
        int n0 = nt * 64;
        float (*Csh)[68] = (float(*)[68])smem_raw;
        float (*Wsh)[68] = (float(*)[68])(smem_raw + 64 * 68 * 4);
        int iq = tid & 15;
        int nq = tid >> 4;
        float acc[4][4] = {};
        for (int kc = 0; kc < DD; kc += 64) {
            __syncthreads();
            {
                int i4 = tid & 15, kk = tid >> 4;
                #pragma unroll
                for (int pass = 0; pass < 4; ++pass) {
                    int k = kk + pass * 16;
                    *((float4*)&Csh[k][i4 * 4]) =
                        *((const float4*)(C + (size_t)(kc + k) * 64 + i4 * 4));
                }
            }
            {
                int n4 = tid & 15, kk = tid >> 4;
                #pragma unroll
                for (int pass = 0; pass < 4; ++pass) {
                    int k = kk + pass * 16;
                    int n = n0 + n4 * 4;
                    float4 v = {0.f, 0.f, 0.f, 0.f};
                    if (n < NY)
                        v = *((const float4*)(W + (size_t)(kc + k) * NY + n));
                    *((float4*)&Wsh[k][n4 * 4]) = v;
                }
            }
            __syncthreads();
            #pragma unroll 4
            for (int k = 0; k < 64; ++k) {
                float4 a = *((float4*)&Csh[k][iq * 4]);
                float4 w = *((float4*)&Wsh[k][nq * 4]);
                float av[4] = {a.x, a.y, a.z, a.w};
                float wv[4] = {w.x, w.y, w.z, w.w};
                #pragma unroll
                for (int ii = 0; ii < 4; ++ii)
                    #pragma unroll
                    for (int nn = 0; nn < 4; ++nn)
                        acc[ii][nn] += av[ii] * wv[nn];
            }
        }
        int n = n0 + nq * 4;
        if (n < NY) {
            #pragma unroll
            for (int ii = 0; ii < 4; ++ii) {
                int i = iq * 4 + ii;
                float4 o = {acc[ii][0], acc[ii][1], acc[ii][2], acc[ii][3]};
                *((float4*)(U + (size_t)i * NY + n)) = o;
            }
        }
    }
}

// ============ PHASE B: inv (block 0) || score tiled GEMM (blocks 1..8) ============
// score rewrite: was 500 blocks x full-C re-read (98 MB L2 + 192-iter serial
// chains). Now 8 blocks of 64 rows, tmat-style tiles.
__global__ __launch_bounds__(256) void k_phaseB(
    const float* __restrict__ gram, const float* __restrict__ cm,
    const float* __restrict__ C, float* __restrict__ ginv,
    float* __restrict__ S) {
    __shared__ __align__(16) char smem_raw[34816];
    int blk = blockIdx.x;
    int tid = threadIdx.x;
    if (blk == 0) {
        // register-resident Gauss-Jordan (verified R3 body)
        int c = tid & 63;
        int q = tid >> 6;
        float a[16], bb[16];
        #pragma unroll
        for (int i = 0; i < 16; ++i) {
            int r = q * 16 + i;
            a[i]  = gram[r * 64 + c];
            bb[i] = (r == c) ? 1.f : 0.f;
        }
        __shared__ float asr[2][64];
        __shared__ float bsr[2][64];
        for (int p = 0; p < 64; ++p) {
            int qp  = p >> 4;
            int lp  = p & 15;
            int par = p & 1;
            if (q == qp) {
                float ap = 0.f, bp = 0.f;
                #pragma unroll
                for (int i = 0; i < 16; ++i)
                    if (i == lp) { ap = a[i]; bp = bb[i]; }
                float App = __shfl(ap, p);
                float s   = 1.0f / App;
                asr[par][c] = ap * s;
                bsr[par][c] = bp * s;
            }
            __syncthreads();
            float as_ = asr[par][c];
            float bs_ = bsr[par][c];
            #pragma unroll
            for (int i = 0; i < 16; ++i) {
                float f = __shfl(a[i], p);
                bool isp = (q == qp) && (i == lp);
                a[i]  = isp ? as_ : fmaf(-f, as_, a[i]);
                bb[i] = isp ? bs_ : fmaf(-f, bs_, bb[i]);
            }
        }
        #pragma unroll
        for (int i = 0; i < 16; ++i)
            ginv[(q * 16 + i) * 64 + c] = bb[i];
    } else {
        // S[500,64] = |cm @ C| / colnorm(C), 64-row tile per block
        int r0 = (blk - 1) * 64;
        float (*Mt)[68] = (float(*)[68])smem_raw;                  // Mt[k][row]
        float (*Cs)[68] = (float(*)[68])(smem_raw + 32 * 68 * 4);  // Cs[k][col]
        int tx = tid & 15;
        int ty = tid >> 4;
        float acc[4][4] = {};
        for (int kc = 0; kc < DD; kc += 32) {
            __syncthreads();
            {
                int row = tid & 63;
                int gr  = r0 + row;
                int grc = gr < NCL ? gr : (NCL - 1);    // clamp; values unused
                int kq  = (tid >> 6) * 2;
                #pragma unroll
                for (int u = 0; u < 2; ++u) {
                    float4 v = *((const float4*)(cm + (size_t)grc * DD + kc + (kq + u) * 4));
                    Mt[(kq + u) * 4 + 0][row] = v.x;
                    Mt[(kq + u) * 4 + 1][row] = v.y;
                    Mt[(kq + u) * 4 + 2][row] = v.z;
                    Mt[(kq + u) * 4 + 3][row] = v.w;
                }
            }
            {
                int c4 = tid & 15;
                int k0 = tid >> 4;
                #pragma unroll
                for (int u = 0; u < 2; ++u) {
                    int kk = k0 + u * 16;
                    *((float4*)&Cs[kk][c4 * 4]) =
                        *((const float4*)(C + (size_t)(kc + kk) * 64 + c4 * 4));
                }
            }
            __syncthreads();
            #pragma unroll 8
            for (int k = 0; k < 32; ++k) {
                float4 ma = *((float4*)&Mt[k][ty * 4]);
                float4 cb = *((float4*)&Cs[k][tx * 4]);
                float mv[4] = {ma.x, ma.y, ma.z, ma.w};
                float cv[4] = {cb.x, cb.y, cb.z, cb.w};
                #pragma unroll
                for (int r = 0; r < 4; ++r)
                    #pragma unroll
                    for (int c = 0; c < 4; ++c)
                        acc[r][c] = fmaf(mv[r], cv[c], acc[r][c]);
            }
        }
        #pragma unroll
        for (int r = 0; r < 4; ++r) {
            int row = r0 + ty * 4 + r;
            if (row < NCL) {
                #pragma unroll
                for (int c = 0; c < 4; ++c) {
                    int col = tx * 4 + c;
                    float nrm = fmaxf(sqrtf(gram[col * 64 + col]), EPSN);
                    S[row * 64 + col] = fabsf(acc[r][c]) / nrm;
                }
            }
        }
    }
}

// ============ PHASE C: y = (T@Ginv)@U + b  (blocks 0..1023) || sparse (1024) ============
// phaseC fold: per block compute T' = T_tile @ Ginv in-LDS (+1024 FMA/thread),
// then T' @ U_tile. Removes the V kernel + one launch gap.
__global__ __launch_bounds__(256) void k_ypred(
    const float* __restrict__ T, const float* __restrict__ ginv,
    const float* __restrict__ U, const float* __restrict__ bh,
    const float* __restrict__ S, float* __restrict__ Y,
    float* __restrict__ out2) {
    __shared__ __align__(16) char smem_raw[66560];
    int blk = blockIdx.x;
    int tid = threadIdx.x;
    if (blk == 1024) {
        // sparse losses from S (verified body)
        __shared__ float colred[4][64];
        __shared__ float rn[64];
        __shared__ float trc[64];
        __shared__ float r1[4], r2[4];
        int c = tid & 63, seg = tid >> 6;
        float p = 0.f;
        for (int r = seg; r < NCL; r += 4) {
            float v = S[r * 64 + c];
            p += v * v;
        }
        colred[seg][c] = p;
        __syncthreads();
        if (seg == 0) {
            float n2  = colred[0][c] + colred[1][c] + colred[2][c] + colred[3][c];
            float inv = 1.0f / fmaxf(sqrtf(n2), EPSN);
            rn[c]  = inv;
            trc[c] = n2 * inv * inv;
        }
        __syncthreads();
        float l1p = 0.f, l2p = 0.f;
        for (int r = tid; r < NCL; r += 256) {
            float rs = 0.f;
            #pragma unroll
            for (int cc = 0; cc < 64; ++cc)
                rs += S[r * 64 + cc] * rn[cc];
            l1p += rs;
            l2p += rs * rs;
        }
        #pragma unroll
        for (int off = 32; off > 0; off >>= 1) {
            l1p += __shfl_down(l1p, off);
            l2p += __shfl_down(l2p, off);
        }
        int wave = tid >> 6, lane = tid & 63;
        if (lane == 0) { r1[wave] = l1p; r2[wave] = l2p; }
        __syncthreads();
        if (tid == 0) {
            float L1 = r1[0] + r1[1] + r1[2] + r1[3];
            float L2 = r2[0] + r2[1] + r2[2] + r2[3];
            float tr = 0.f;
            #pragma unroll
            for (int cc = 0; cc < 64; ++cc) tr += trc[cc];
            out2[0] = L1;
            out2[1] = L2 - tr;
        }
        return;
    }
    float (*Ts)[68]  = (float(*)[68])smem_raw;                   // Ts[k][row], later T2[j][row]
    float (*Gs)[64]  = (float(*)[64])(smem_raw + 64 * 68 * 4);   // Ginv[k][j]
    float (*Vs)[128] = (float(*)[128])(smem_raw + 64 * 68 * 4 + 64 * 64 * 4); // U[k][n]
    int rb  = blk >> 3, cb = blk & 7;
    int r0g = rb * 64;
    int c0g = cb * 128;
    {   // stage T transposed: Ts[k][row]
        int kf = tid & 15;
        int rr = tid >> 4;
        #pragma unroll
        for (int pass = 0; pass < 4; ++pass) {
            int row = rr + pass * 16;
            float4 a = *((const float4*)(T + (size_t)(r0g + row) * 64 + kf * 4));
            Ts[kf * 4 + 0][row] = a.x;
            Ts[kf * 4 + 1][row] = a.y;
            Ts[kf * 4 + 2][row] = a.z;
            Ts[kf * 4 + 3][row] = a.w;
        }
    }
    {   // stage Ginv [64][64], coalesced float4
        #pragma unroll
        for (int p = 0; p < 4; ++p) {
            int f = tid + p * 256;          // 1024 float4s
            int k = f >> 4, j4 = f & 15;
            *((float4*)&Gs[k][j4 * 4]) = *((const float4*)(ginv + k * 64 + j4 * 4));
        }
    }
    {   // stage U tile (zero-pad cols >= 1000)
        int cf = tid & 31;
        int kk = tid >> 5;
        #pragma unroll
        for (int pass = 0; pass < 8; ++pass) {
            int k = kk + pass * 8;
            int c = c0g + cf * 4;
            float4 v = {0.f, 0.f, 0.f, 0.f};
            if (c < NY) v = *((const float4*)(U + (size_t)k * NY + c));
            *((float4*)&Vs[k][cf * 4]) = v;
        }
    }
    __syncthreads();
    // T' = T_tile @ Ginv : thread (tx=j-quad, ty=row-quad)
    int tx = tid & 15;
    int ty = tid >> 4;
    float tp[4][4] = {};
    #pragma unroll 4
    for (int k = 0; k < 64; ++k) {
        float4 a = *((float4*)&Ts[k][ty * 4]);
        float4 g = *((float4*)&Gs[k][tx * 4]);
        float av[4] = {a.x, a.y, a.z, a.w};
        float gv[4] = {g.x, g.y, g.z, g.w};
        #pragma unroll
        for (int r = 0; r < 4; ++r)
            #pragma unroll
            for (int j = 0; j < 4; ++j)
                tp[r][j] = fmaf(av[r], gv[j], tp[r][j]);
    }
    __syncthreads();                 // all Ts reads done
    // write T2[j][row] into Ts buffer
    #pragma unroll
    for (int j = 0; j < 4; ++j)
        #pragma unroll
        for (int r = 0; r < 4; ++r)
            Ts[tx * 4 + j][ty * 4 + r] = tp[r][j];
    __syncthreads();
    // y_tile = T2^T @ U_tile (same loop as before; Ts holds T2[j][row])
    int cx = tid & 15;
    int ry = tid >> 4;
    float acc[4][8] = {};
    #pragma unroll 2
    for (int k = 0; k < 64; ++k) {
        float4 a  = *((float4*)&Ts[k][ry * 4]);
        float4 b0 = *((float4*)&Vs[k][cx * 8]);
        float4 b1 = *((float4*)&Vs[k][cx * 8 + 4]);
        float av[4] = {a.x, a.y, a.z, a.w};
        float bv[8] = {b0.x, b0.y, b0.z, b0.w, b1.x, b1.y, b1.z, b1.w};
        #pragma unroll
        for (int r = 0; r < 4; ++r)
            #pragma unroll
            for (int c = 0; c < 8; ++c)
                acc[r][c] += av[r] * bv[c];
    }
    #pragma unroll
    for (int r = 0; r < 4; ++r) {
        int row   = r0g + ry * 4 + r;
        int cbase = c0g + cx * 8;
        #pragma unroll
        for (int cq = 0; cq < 2; ++cq) {
            int c = cbase + cq * 4;
            if (c < NY) {
                float4 o;
                o.x = acc[r][cq * 4 + 0] + bh[c + 0];
                o.y = acc[r][cq * 4 + 1] + bh[c + 1];
                o.z = acc[r][cq * 4 + 2] + bh[c + 2];
                o.w = acc[r][cq * 4 + 3] + bh[c + 3];
                *((float4*)(Y + (size_t)row * NY + c)) = o;
            }
        }
    }
}

extern "C" void kernel_launch(void* const* d_in, const int* in_sizes, int n_in,
                              void* d_out, int out_size, void* d_ws, size_t ws_size,
                              hipStream_t stream) {
    const float* X        = (const float*)d_in[0];   // [8192,768]
    const float* clusters = (const float*)d_in[1];   // [500,100,768]
    const float* C        = (const float*)d_in[2];   // [768,64]
    const float* W        = (const float*)d_in[3];   // [768,1000]
    const float* bh       = (const float*)d_in[4];   // [1000]
    float* out = (float*)d_out;                      // y_pred, L1, L2
    float* ws  = (float*)d_ws;

    float* cm   = ws;                 // 500*768   = 384000
    float* gram = cm   + 384000;      // 4096
    float* ginv = gram + 4096;        // 4096
    float* U    = ginv + 4096;        // 64*1000   = 64000
    float* T    = U    + 64000;       // 8192*64   = 524288
    float* S    = T    + 524288;      // 500*64    = 32000

    k_phaseA<<<dim3(NB_A), dim3(256), 0, stream>>>(clusters, C, W, X, cm, gram, U, T);
    k_phaseB<<<dim3(9),    dim3(256), 0, stream>>>(gram, cm, C, ginv, S);
    k_ypred <<<dim3(1025), dim3(256), 0, stream>>>(T, ginv, U, bh, S, out, out + (size_t)BS * NY);
}

// Round 7
// 174.215 us; speedup vs baseline: 1.1854x; 1.0087x over previous
//
#include <hip/hip_runtime.h>
#include <math.h>

#define BS   8192
#define DD   768
#define NC   64
#define NCL  500
#define CS   100
#define NY   1000
#define EPSN 1e-12f

// phaseA roles: tmat first (256 blocks -> ~1/CU), then cmean stream, gram, U.
#define NB_TMAT  256   // 64 row-tiles(128) x 4 k-splits(192)
#define NB_CMEAN 375
#define NB_GRAM  64
#define NB_U     32    // 8 n-tiles(128) x 4 k-splits(192)
#define NB_A     (NB_TMAT + NB_CMEAN + NB_GRAM + NB_U)

#define FMA4(acc, s, v) { (acc).x = fmaf((s), (v).x, (acc).x); \
                          (acc).y = fmaf((s), (v).y, (acc).y); \
                          (acc).z = fmaf((s), (v).z, (acc).z); \
                          (acc).w = fmaf((s), (v).w, (acc).w); }

// ============ PHASE A: tmat(ksplit) || cmean || gram || U(ksplit) ============
__global__ __launch_bounds__(256) void k_phaseA(
    const float* __restrict__ clusters, const float* __restrict__ C,
    const float* __restrict__ W, const float* __restrict__ X,
    float* __restrict__ cm, float* __restrict__ gram,
    float* __restrict__ Up, float* __restrict__ Tp) {
    __shared__ __align__(16) char smem_raw[25600];
    int b   = blockIdx.x;
    int tid = threadIdx.x;

    if (b < NB_TMAT) {
        // T-partial = X[tile rows][k-slice] @ C[k-slice][64].
        // 8x4 thread tile: 3 ds_read_b128 per 32 FMA (was 2/16) and 256-block
        // spread: per-block LDS-pipe time ~2048 instr*12cy ~ 10us (was 31).
        int tile = b >> 2, ks = b & 3;
        int r0g  = tile * 128, kb = ks * 192;
        float (*Xt)[132] = (float(*)[132])smem_raw;              // [32][132] Xt[k][row]
        float (*Cs)[68]  = (float(*)[68])(smem_raw + 16896);     // [32][68]  Cs[k][col]
        int tx = tid & 15, ty = tid >> 4;    // cols tx*4..+3, rows ty*8..+7
        float4 acc[8];
        #pragma unroll
        for (int r = 0; r < 8; ++r) acc[r] = make_float4(0.f, 0.f, 0.f, 0.f);
        for (int kc = kb; kc < kb + 192; kc += 32) {
            __syncthreads();
            {   // stage X transposed: 128 rows x 32 k
                int row = tid & 127, kh = (tid >> 7) * 16;
                const float4* xp = (const float4*)(X + (size_t)(r0g + row) * DD + kc + kh);
                float4 x0 = xp[0], x1 = xp[1], x2 = xp[2], x3 = xp[3];
                Xt[kh+ 0][row]=x0.x; Xt[kh+ 1][row]=x0.y; Xt[kh+ 2][row]=x0.z; Xt[kh+ 3][row]=x0.w;
                Xt[kh+ 4][row]=x1.x; Xt[kh+ 5][row]=x1.y; Xt[kh+ 6][row]=x1.z; Xt[kh+ 7][row]=x1.w;
                Xt[kh+ 8][row]=x2.x; Xt[kh+ 9][row]=x2.y; Xt[kh+10][row]=x2.z; Xt[kh+11][row]=x2.w;
                Xt[kh+12][row]=x3.x; Xt[kh+13][row]=x3.y; Xt[kh+14][row]=x3.z; Xt[kh+15][row]=x3.w;
            }
            {   // stage C chunk: 32 k x 64 cols
                int c4 = tid & 15, kk = tid >> 4;
                *((float4*)&Cs[kk][c4*4])      = *((const float4*)(C + (size_t)(kc+kk)*64 + c4*4));
                *((float4*)&Cs[kk+16][c4*4])   = *((const float4*)(C + (size_t)(kc+kk+16)*64 + c4*4));
            }
            __syncthreads();
            #pragma unroll 8
            for (int k = 0; k < 32; ++k) {
                float4 xa = *((float4*)&Xt[k][ty*8]);
                float4 xb = *((float4*)&Xt[k][ty*8+4]);
                float4 cb = *((float4*)&Cs[k][tx*4]);
                FMA4(acc[0], xa.x, cb); FMA4(acc[1], xa.y, cb);
                FMA4(acc[2], xa.z, cb); FMA4(acc[3], xa.w, cb);
                FMA4(acc[4], xb.x, cb); FMA4(acc[5], xb.y, cb);
                FMA4(acc[6], xb.z, cb); FMA4(acc[7], xb.w, cb);
            }
        }
        float* Tps = Tp + (size_t)ks * BS * 64;
        #pragma unroll
        for (int r = 0; r < 8; ++r)
            *((float4*)(Tps + (size_t)(r0g + ty*8 + r) * 64 + tx*4)) = acc[r];
    } else if (b < NB_TMAT + NB_CMEAN) {
        // ---- cluster_mean, 4-acc unrolled streaming ----
        int idx = (b - NB_TMAT) * 256 + tid;
        int r  = idx / (DD / 4);
        int d4 = idx % (DD / 4);
        const float4* base = (const float4*)(clusters + (size_t)r * CS * DD) + d4;
        float4 a0 = {0,0,0,0}, a1 = {0,0,0,0}, a2 = {0,0,0,0}, a3 = {0,0,0,0};
        for (int s = 0; s < CS; s += 4) {
            float4 v0 = base[(size_t)(s + 0) * (DD / 4)];
            float4 v1 = base[(size_t)(s + 1) * (DD / 4)];
            float4 v2 = base[(size_t)(s + 2) * (DD / 4)];
            float4 v3 = base[(size_t)(s + 3) * (DD / 4)];
            a0.x += v0.x; a0.y += v0.y; a0.z += v0.z; a0.w += v0.w;
            a1.x += v1.x; a1.y += v1.y; a1.z += v1.z; a1.w += v1.w;
            a2.x += v2.x; a2.y += v2.y; a2.z += v2.z; a2.w += v2.w;
            a3.x += v3.x; a3.y += v3.y; a3.z += v3.z; a3.w += v3.w;
        }
        float4 o;
        const float sc = 1.0f / CS;
        o.x = (a0.x + a1.x + a2.x + a3.x) * sc;
        o.y = (a0.y + a1.y + a2.y + a3.y) * sc;
        o.z = (a0.z + a1.z + a2.z + a3.z) * sc;
        o.w = (a0.w + a1.w + a2.w + a3.w) * sc;
        ((float4*)cm)[idx] = o;
    } else if (b < NB_TMAT + NB_CMEAN + NB_GRAM) {
        // ---- gram = C^T C [64,64] ----
        int j   = b - (NB_TMAT + NB_CMEAN);
        int i   = tid & 63;
        int seg = tid >> 6;
        float p = 0.f;
        for (int k = seg * 192; k < seg * 192 + 192; ++k)
            p += C[k * NC + i] * C[k * NC + j];
        float (*red)[64] = (float(*)[64])smem_raw;
        red[seg][i] = p;
        __syncthreads();
        if (seg == 0)
            gram[i * NC + j] = red[0][i] + red[1][i] + red[2][i] + red[3][i];
    } else {
        // ---- U-partial = C^T[64 x kslice] W[kslice x 128-col tile] ----
        int q  = b - (NB_TMAT + NB_CMEAN + NB_GRAM);
        int nt = q >> 2, ks = q & 3;
        int n0 = nt * 128, kb = ks * 192;
        float (*Cu)[68]  = (float(*)[68])smem_raw;               // [32][68]  Cu[k][i]
        float (*Wu)[132] = (float(*)[132])(smem_raw + 8704);     // [32][132] Wu[k][n]
        int tx = tid & 15, ty = tid >> 4;    // n cols n0+tx*8..+7, i rows ty*4..+3
        float4 a0[4], a1[4];
        #pragma unroll
        for (int i = 0; i < 4; ++i) { a0[i] = make_float4(0,0,0,0); a1[i] = make_float4(0,0,0,0); }
        for (int kc = kb; kc < kb + 192; kc += 32) {
            __syncthreads();
            {   int i4 = tid & 15, kk = tid >> 4;
                *((float4*)&Cu[kk][i4*4])    = *((const float4*)(C + (size_t)(kc+kk)*64 + i4*4));
                *((float4*)&Cu[kk+16][i4*4]) = *((const float4*)(C + (size_t)(kc+kk+16)*64 + i4*4));
            }
            {   int nf = tid & 31, kq = tid >> 5;
                #pragma unroll
                for (int u = 0; u < 4; ++u) {
                    int k = kq + u * 8;
                    int n = n0 + nf * 4;
                    float4 v = {0.f, 0.f, 0.f, 0.f};
                    if (n < NY) v = *((const float4*)(W + (size_t)(kc + k) * NY + n));
                    *((float4*)&Wu[k][nf*4]) = v;
                }
            }
            __syncthreads();
            #pragma unroll 8
            for (int k = 0; k < 32; ++k) {
                float4 ci = *((float4*)&Cu[k][ty*4]);
                float4 w0 = *((float4*)&Wu[k][tx*8]);
                float4 w1 = *((float4*)&Wu[k][tx*8+4]);
                FMA4(a0[0], ci.x, w0); FMA4(a1[0], ci.x, w1);
                FMA4(a0[1], ci.y, w0); FMA4(a1[1], ci.y, w1);
                FMA4(a0[2], ci.z, w0); FMA4(a1[2], ci.z, w1);
                FMA4(a0[3], ci.w, w0); FMA4(a1[3], ci.w, w1);
            }
        }
        float* Ups = Up + (size_t)ks * 64000;
        #pragma unroll
        for (int i = 0; i < 4; ++i) {
            int irow = ty * 4 + i;
            int n = n0 + tx * 8;
            if (n < NY)     *((float4*)(Ups + (size_t)irow * NY + n))     = a0[i];
            if (n + 4 < NY) *((float4*)(Ups + (size_t)irow * NY + n + 4)) = a1[i];
        }
    }
}

// ============ PHASE B: inv (block 0) || score partials (blocks 1..16) ============
__global__ __launch_bounds__(256) void k_phaseB(
    const float* __restrict__ gram, const float* __restrict__ cm,
    const float* __restrict__ C, float* __restrict__ ginv,
    float* __restrict__ SP) {
    __shared__ __align__(16) char smem_raw[25600];
    int blk = blockIdx.x;
    int tid = threadIdx.x;
    if (blk == 0) {
        // register-resident Gauss-Jordan (verified R3 body)
        int c = tid & 63;
        int q = tid >> 6;
        float a[16], bb[16];
        #pragma unroll
        for (int i = 0; i < 16; ++i) {
            int r = q * 16 + i;
            a[i]  = gram[r * 64 + c];
            bb[i] = (r == c) ? 1.f : 0.f;
        }
        __shared__ float asr[2][64];
        __shared__ float bsr[2][64];
        for (int p = 0; p < 64; ++p) {
            int qp  = p >> 4;
            int lp  = p & 15;
            int par = p & 1;
            if (q == qp) {
                float ap = 0.f, bp = 0.f;
                #pragma unroll
                for (int i = 0; i < 16; ++i)
                    if (i == lp) { ap = a[i]; bp = bb[i]; }
                float App = __shfl(ap, p);
                float s   = 1.0f / App;
                asr[par][c] = ap * s;
                bsr[par][c] = bp * s;
            }
            __syncthreads();
            float as_ = asr[par][c];
            float bs_ = bsr[par][c];
            #pragma unroll
            for (int i = 0; i < 16; ++i) {
                float f = __shfl(a[i], p);
                bool isp = (q == qp) && (i == lp);
                a[i]  = isp ? as_ : fmaf(-f, as_, a[i]);
                bb[i] = isp ? bs_ : fmaf(-f, bs_, bb[i]);
            }
        }
        #pragma unroll
        for (int i = 0; i < 16; ++i)
            ginv[(q * 16 + i) * 64 + c] = bb[i];
    } else {
        // SP-partial[ks] = cm[tile rows][kslice] @ C[kslice][64]  (RAW, no abs:
        // abs is non-linear -> applied after summing partials in the sparse block)
        int q = blk - 1;                  // 0..15
        int tile = q >> 2, ks = q & 3;
        int r0 = tile * 128, kb = ks * 192;
        float (*Mt)[132] = (float(*)[132])smem_raw;
        float (*Cs)[68]  = (float(*)[68])(smem_raw + 16896);
        int tx = tid & 15, ty = tid >> 4;
        float4 acc[8];
        #pragma unroll
        for (int r = 0; r < 8; ++r) acc[r] = make_float4(0.f, 0.f, 0.f, 0.f);
        for (int kc = kb; kc < kb + 192; kc += 32) {
            __syncthreads();
            {   int row = tid & 127, kh = (tid >> 7) * 16;
                int gr = r0 + row;
                int grc = gr < NCL ? gr : (NCL - 1);     // clamp; garbage unused
                const float4* xp = (const float4*)(cm + (size_t)grc * DD + kc + kh);
                float4 x0 = xp[0], x1 = xp[1], x2 = xp[2], x3 = xp[3];
                Mt[kh+ 0][row]=x0.x; Mt[kh+ 1][row]=x0.y; Mt[kh+ 2][row]=x0.z; Mt[kh+ 3][row]=x0.w;
                Mt[kh+ 4][row]=x1.x; Mt[kh+ 5][row]=x1.y; Mt[kh+ 6][row]=x1.z; Mt[kh+ 7][row]=x1.w;
                Mt[kh+ 8][row]=x2.x; Mt[kh+ 9][row]=x2.y; Mt[kh+10][row]=x2.z; Mt[kh+11][row]=x2.w;
                Mt[kh+12][row]=x3.x; Mt[kh+13][row]=x3.y; Mt[kh+14][row]=x3.z; Mt[kh+15][row]=x3.w;
            }
            {   int c4 = tid & 15, kk = tid >> 4;
                *((float4*)&Cs[kk][c4*4])    = *((const float4*)(C + (size_t)(kc+kk)*64 + c4*4));
                *((float4*)&Cs[kk+16][c4*4]) = *((const float4*)(C + (size_t)(kc+kk+16)*64 + c4*4));
            }
            __syncthreads();
            #pragma unroll 8
            for (int k = 0; k < 32; ++k) {
                float4 xa = *((float4*)&Mt[k][ty*8]);
                float4 xb = *((float4*)&Mt[k][ty*8+4]);
                float4 cb = *((float4*)&Cs[k][tx*4]);
                FMA4(acc[0], xa.x, cb); FMA4(acc[1], xa.y, cb);
                FMA4(acc[2], xa.z, cb); FMA4(acc[3], xa.w, cb);
                FMA4(acc[4], xb.x, cb); FMA4(acc[5], xb.y, cb);
                FMA4(acc[6], xb.z, cb); FMA4(acc[7], xb.w, cb);
            }
        }
        float* SPs = SP + (size_t)ks * 32000;
        #pragma unroll
        for (int r = 0; r < 8; ++r) {
            int row = r0 + ty * 8 + r;
            if (row < NCL)
                *((float4*)(SPs + (size_t)row * 64 + tx*4)) = acc[r];
        }
    }
}

// ===== PHASE C: y = (sum Tp)@Ginv@(sum Up) + b (blocks 0..1023) || sparse (1024) =====
__global__ __launch_bounds__(256) void k_ypred(
    const float* __restrict__ Tp, const float* __restrict__ ginv,
    const float* __restrict__ Up, const float* __restrict__ bh,
    float* __restrict__ SP, float* __restrict__ Y,
    float* __restrict__ out2) {
    __shared__ __align__(16) char smem_raw[67584];
    int blk = blockIdx.x;
    int tid = threadIdx.x;
    if (blk == 1024) {
        // sparse losses: sum 4 SP partials -> abs -> colnorm -> L1/L2
        __shared__ float colred[4][64];
        __shared__ float rn[64];
        __shared__ float trc[64];
        __shared__ float r1[4], r2[4];
        const float* SP0 = SP;
        const float* SP1 = SP + 32000;
        const float* SP2 = SP + 64000;
        const float* SP3 = SP + 96000;
        int c = tid & 63, seg = tid >> 6;
        float p = 0.f;
        for (int r = seg; r < NCL; r += 4) {
            int off = r * 64 + c;
            float s = fabsf(SP0[off] + SP1[off] + SP2[off] + SP3[off]);
            SP[off] = s;                 // cache summed |S|; only this block uses SP
            p += s * s;
        }
        colred[seg][c] = p;
        __syncthreads();
        if (seg == 0) {
            float n2  = colred[0][c] + colred[1][c] + colred[2][c] + colred[3][c];
            float inv = 1.0f / fmaxf(sqrtf(n2), EPSN);
            rn[c]  = inv;
            trc[c] = n2 * inv * inv;
        }
        __syncthreads();
        float l1p = 0.f, l2p = 0.f;
        for (int r = tid; r < NCL; r += 256) {
            float rs = 0.f;
            #pragma unroll
            for (int cc = 0; cc < 64; ++cc)
                rs += SP[r * 64 + cc] * rn[cc];
            l1p += rs;
            l2p += rs * rs;
        }
        #pragma unroll
        for (int off = 32; off > 0; off >>= 1) {
            l1p += __shfl_down(l1p, off);
            l2p += __shfl_down(l2p, off);
        }
        int wave = tid >> 6, lane = tid & 63;
        if (lane == 0) { r1[wave] = l1p; r2[wave] = l2p; }
        __syncthreads();
        if (tid == 0) {
            float L1 = r1[0] + r1[1] + r1[2] + r1[3];
            float L2 = r2[0] + r2[1] + r2[2] + r2[3];
            float tr = 0.f;
            #pragma unroll
            for (int cc = 0; cc < 64; ++cc) tr += trc[cc];
            out2[0] = L1;
            out2[1] = L2 - tr;
        }
        return;
    }
    float (*Ts)[132] = (float(*)[132])smem_raw;                // T then T2, [64/k][132]
    float (*Gs)[64]  = (float(*)[64])(smem_raw + 33792);       // Ginv[k][j]
    float (*Vs)[68]  = (float(*)[68])(smem_raw + 50176);       // U[j][n-tile]
    int rb = blk >> 4, cb = blk & 15;
    int r0g = rb * 128, c0g = cb * 64;
    const float* Tp0 = Tp;
    const float* Tp1 = Tp + (size_t)BS * 64;
    const float* Tp2 = Tp + (size_t)BS * 128;
    const float* Tp3 = Tp + (size_t)BS * 192;
    const float* Up0 = Up;
    const float* Up1 = Up + 64000;
    const float* Up2 = Up + 128000;
    const float* Up3 = Up + 192000;
    {   // stage T = sum of 4 partials, transposed: Ts[k][row]
        int kf = tid & 15, rr = tid >> 4;
        #pragma unroll
        for (int p = 0; p < 8; ++p) {
            int row = rr + p * 16;
            size_t off = (size_t)(r0g + row) * 64 + kf * 4;
            float4 t0 = *((const float4*)(Tp0 + off));
            float4 t1 = *((const float4*)(Tp1 + off));
            float4 t2 = *((const float4*)(Tp2 + off));
            float4 t3 = *((const float4*)(Tp3 + off));
            float4 t;
            t.x = t0.x + t1.x + t2.x + t3.x;
            t.y = t0.y + t1.y + t2.y + t3.y;
            t.z = t0.z + t1.z + t2.z + t3.z;
            t.w = t0.w + t1.w + t2.w + t3.w;
            Ts[kf*4+0][row] = t.x; Ts[kf*4+1][row] = t.y;
            Ts[kf*4+2][row] = t.z; Ts[kf*4+3][row] = t.w;
        }
    }
    {   // stage Ginv
        #pragma unroll
        for (int p = 0; p < 4; ++p) {
            int f = tid + p * 256;
            int k = f >> 4, j4 = f & 15;
            *((float4*)&Gs[k][j4*4]) = *((const float4*)(ginv + k * 64 + j4*4));
        }
    }
    {   // stage U tile = sum of 4 partials (zero-pad n >= 1000)
        #pragma unroll
        for (int p = 0; p < 4; ++p) {
            int f = tid + p * 256;
            int k = f >> 4, n4 = f & 15;
            int n = c0g + n4 * 4;
            float4 v = {0.f, 0.f, 0.f, 0.f};
            if (n < NY) {
                float4 u0 = *((const float4*)(Up0 + (size_t)k * NY + n));
                float4 u1 = *((const float4*)(Up1 + (size_t)k * NY + n));
                float4 u2 = *((const float4*)(Up2 + (size_t)k * NY + n));
                float4 u3 = *((const float4*)(Up3 + (size_t)k * NY + n));
                v.x = u0.x + u1.x + u2.x + u3.x;
                v.y = u0.y + u1.y + u2.y + u3.y;
                v.z = u0.z + u1.z + u2.z + u3.z;
                v.w = u0.w + u1.w + u2.w + u3.w;
            }
            *((float4*)&Vs[k][n4*4]) = v;
        }
    }
    __syncthreads();
    // fold: T2[row][j] = sum_k T[row][k] Ginv[k][j]; thread: rows ty*8..+7, j tx*4..+3
    int tx = tid & 15, ty = tid >> 4;
    float4 tp[8];
    #pragma unroll
    for (int r = 0; r < 8; ++r) tp[r] = make_float4(0.f, 0.f, 0.f, 0.f);
    #pragma unroll 8
    for (int k = 0; k < 64; ++k) {
        float4 xa = *((float4*)&Ts[k][ty*8]);
        float4 xb = *((float4*)&Ts[k][ty*8+4]);
        float4 g  = *((float4*)&Gs[k][tx*4]);
        FMA4(tp[0], xa.x, g); FMA4(tp[1], xa.y, g);
        FMA4(tp[2], xa.z, g); FMA4(tp[3], xa.w, g);
        FMA4(tp[4], xb.x, g); FMA4(tp[5], xb.y, g);
        FMA4(tp[6], xb.z, g); FMA4(tp[7], xb.w, g);
    }
    __syncthreads();                  // all Ts reads complete
    #pragma unroll
    for (int r = 0; r < 8; ++r) {
        int row = ty * 8 + r;
        Ts[tx*4+0][row] = tp[r].x;
        Ts[tx*4+1][row] = tp[r].y;
        Ts[tx*4+2][row] = tp[r].z;
        Ts[tx*4+3][row] = tp[r].w;
    }
    __syncthreads();
    // y = T2 @ U_tile + b; thread: rows ry*8..+7, cols cx*4..+3
    int cx = tid & 15, ry = tid >> 4;
    float4 acc[8];
    #pragma unroll
    for (int r = 0; r < 8; ++r) acc[r] = make_float4(0.f, 0.f, 0.f, 0.f);
    #pragma unroll 8
    for (int k = 0; k < 64; ++k) {
        float4 xa = *((float4*)&Ts[k][ry*8]);
        float4 xb = *((float4*)&Ts[k][ry*8+4]);
        float4 v  = *((float4*)&Vs[k][cx*4]);
        FMA4(acc[0], xa.x, v); FMA4(acc[1], xa.y, v);
        FMA4(acc[2], xa.z, v); FMA4(acc[3], xa.w, v);
        FMA4(acc[4], xb.x, v); FMA4(acc[5], xb.y, v);
        FMA4(acc[6], xb.z, v); FMA4(acc[7], xb.w, v);
    }
    int col = c0g + cx * 4;
    if (col < NY) {
        float4 bias = *((const float4*)(bh + col));
        #pragma unroll
        for (int r = 0; r < 8; ++r) {
            int row = r0g + ry * 8 + r;
            float4 o;
            o.x = acc[r].x + bias.x;
            o.y = acc[r].y + bias.y;
            o.z = acc[r].z + bias.z;
            o.w = acc[r].w + bias.w;
            *((float4*)(Y + (size_t)row * NY + col)) = o;
        }
    }
}

extern "C" void kernel_launch(void* const* d_in, const int* in_sizes, int n_in,
                              void* d_out, int out_size, void* d_ws, size_t ws_size,
                              hipStream_t stream) {
    const float* X        = (const float*)d_in[0];   // [8192,768]
    const float* clusters = (const float*)d_in[1];   // [500,100,768]
    const float* C        = (const float*)d_in[2];   // [768,64]
    const float* W        = (const float*)d_in[3];   // [768,1000]
    const float* bh       = (const float*)d_in[4];   // [1000]
    float* out = (float*)d_out;                      // y_pred, L1, L2
    float* ws  = (float*)d_ws;

    float* cm   = ws;                   // 384000
    float* gram = cm   + 384000;        // 4096
    float* ginv = gram + 4096;          // 4096
    float* Up   = ginv + 4096;          // 4 x 64000  = 256000
    float* SP   = Up   + 256000;        // 4 x 32000  = 128000
    float* Tp   = SP   + 128000;        // 4 x 524288 = 2097152
                                        // total ~11.5 MB of d_ws

    k_phaseA<<<dim3(NB_A), dim3(256), 0, stream>>>(clusters, C, W, X, cm, gram, Up, Tp);
    k_phaseB<<<dim3(17),   dim3(256), 0, stream>>>(gram, cm, C, ginv, SP);
    k_ypred <<<dim3(1025), dim3(256), 0, stream>>>(Tp, ginv, Up, bh, SP, out, out + (size_t)BS * NY);
}